// Round 14
// baseline (111.721 us; speedup 1.0000x reference)
//
#include <hip/hip_runtime.h>
#include <stdint.h>

typedef unsigned long long u64;
typedef unsigned int u32;

#define NC 80
#define CONF_T 0.25f
#define IOU_THR 0.45f
#define MAX_DET 300
#define KBIG 1024
#define A_ANCH 8400
#define NROWS 84
#define MAX_WH 7680.0f
#define HBINS 256
#define BIN_BASE 0x3e80u

// adaptive wave histogram add
__device__ __forceinline__ void hadd(u32* h, u32 bin, bool m, int lane) {
    u64 act = __ballot(m);
    if (act == 0) return;
    int fl = __ffsll((unsigned long long)act) - 1;
    u32 fb = __shfl(bin, fl);
    u64 same = __ballot(m && (bin == fb));
    if (lane == fl) atomicAdd(&h[fb], (u32)__popcll(same));
    if (m && (bin != fb)) atomicAdd(&h[bin], 1u);
}

// ---------------- Kernel 1: conf/argmax -> keys; slab 0 zeroes hist ----------------
__global__ __launch_bounds__(512) void yolo_conf_kernel(const float* __restrict__ preds,
                                                        u64* __restrict__ keys,
                                                        u32* __restrict__ hist) {
    int b = blockIdx.x / 9;
    int slab = blockIdx.x % 9;
    if (slab == 0 && threadIdx.x < HBINS) hist[(size_t)b * HBINS + threadIdx.x] = 0;
    int g = slab * 512 + threadIdx.x;
    if (g >= A_ANCH / 2) return;
    int a0 = g * 2;
    const float* base = preds + ((size_t)b * NROWS + 4) * A_ANCH + a0;
    float2 best = *(const float2*)base;
    int bc0 = 0, bc1 = 0;
#pragma unroll 8
    for (int c = 1; c < NC; ++c) {
        float2 v = *(const float2*)(base + (size_t)c * A_ANCH);
        if (v.x > best.x) { best.x = v.x; bc0 = c; }   // strict > = first-max argmax
        if (v.y > best.y) { best.y = v.y; bc1 = c; }
    }
    float s0 = (best.x > CONF_T) ? best.x : 0.0f;
    float s1 = (best.y > CONF_T) ? best.y : 0.0f;
    ulonglong2 kk;
    kk.x = ((u64)__float_as_uint(s0) << 32) | ((u64)(16383 - a0) << 7) | (u64)bc0;
    kk.y = ((u64)__float_as_uint(s1) << 32) | ((u64)(16383 - (a0 + 1)) << 7) | (u64)bc1;
    *(ulonglong2*)(keys + (size_t)b * A_ANCH + a0) = kk;
}

// ---------------- Kernel 2: prep — obox + 256-bin hist ----------------
__global__ __launch_bounds__(256) void yolo_prep_kernel(const float* __restrict__ preds,
                                                        const u64* __restrict__ keys,
                                                        float4* __restrict__ obox,
                                                        u32* __restrict__ hist) {
    __shared__ u32 lh[HBINS];
    const int lane = threadIdx.x & 63;
    int b = blockIdx.x / 33;
    int a = (blockIdx.x % 33) * 256 + threadIdx.x;
    lh[threadIdx.x] = 0;
    __syncthreads();
    u32 bits = 0, bin = 0;
    bool act = a < A_ANCH;
    if (act) {
        u64 key = keys[(size_t)b * A_ANCH + a];
        bits = (u32)(key >> 32);
        int cls = (int)(key & 127u);
        const float* pb = preds + (size_t)b * NROWS * A_ANCH + a;
        float x = pb[0];
        float y = pb[A_ANCH];
        float w = pb[2 * A_ANCH];
        float h = pb[3 * A_ANCH];
        float hw = __fmul_rn(w, 0.5f), hh = __fmul_rn(h, 0.5f);
        float x1 = __fsub_rn(x, hw), x2 = __fadd_rn(x, hw);
        float y1 = __fsub_rn(y, hh), y2 = __fadd_rn(y, hh);
        float off = __fmul_rn((float)cls, MAX_WH);
        float4 oB;
        oB.x = __fadd_rn(x1, off); oB.y = __fadd_rn(y1, off);
        oB.z = __fadd_rn(x2, off); oB.w = __fadd_rn(y2, off);
        obox[(size_t)b * A_ANCH + a] = oB;
        bin = (bits >> 16) - BIN_BASE;
        if (bin > 255u) bin = 255u;
    }
    hadd(lh, bin, act && (bits != 0u), lane);
    __syncthreads();
    u32 c = lh[threadIdx.x];
    if (c) atomicAdd(&hist[(size_t)b * HBINS + threadIdx.x], c);
}

__device__ __forceinline__ float iou_f(float ix1, float iy1, float ix2, float iy2, float iar,
                                       float jx1, float jy1, float jx2, float jy2, float jar) {
    float lx = fmaxf(ix1, jx1), ly = fmaxf(iy1, jy1);
    float rx = fminf(ix2, jx2), ry = fminf(iy2, jy2);
    float ww = fmaxf(__fsub_rn(rx, lx), 0.0f);
    float hh = fmaxf(__fsub_rn(ry, ly), 0.0f);
    float inter = __fmul_rn(ww, hh);
    float den = __fadd_rn(__fsub_rn(__fadd_rn(iar, jar), inter), 1e-7f);
    return __fdiv_rn(inter, den);
}

__device__ __forceinline__ u64 bstep(u64 v, u32 idx, u32 size, u32 stride) {
    u64 v2 = __shfl_xor((unsigned long long)v, (int)stride, 64);
    bool keep_big = (((idx & stride) == 0) == ((idx & size) == 0));
    return ((v > v2) == keep_big) ? v : v2;
}

__device__ __forceinline__ void radix_scan(u32* hist, int nb, int shift, u32* s_scal,
                                           u32* wsum, int tid, int lane, int wid) {
    int per = nb >> 9; if (per == 0) per = 1;
    int na = nb / per;
    u32 rem = s_scal[1];
    u32 Pk = s_scal[0];
    int hi = nb - 1 - per * tid;
    u32 s = 0;
    if (tid < na)
        for (int q = 0; q < per; ++q) s += hist[hi - q];
    u32 pre = s;
#pragma unroll
    for (int off = 1; off < 64; off <<= 1) {
        u32 o = __shfl_up(pre, off);
        if (lane >= off) pre += o;
    }
    if (lane == 63) wsum[wid] = pre;
    __syncthreads();
    u32 base = 0;
    for (int w = 0; w < wid; ++w) base += wsum[w];
    u32 run = base + pre - s;
    if (tid < na) {
        for (int q = 0; q < per; ++q) {
            int d = hi - q;
            u32 g = hist[d];
            if (run < rem && rem <= run + g) {
                s_scal[0] = Pk | ((u32)d << shift);
                s_scal[1] = rem - run;
            }
            run += g;
        }
    }
    __syncthreads();
}

// ---------------- Kernel 3: sel_sort — hist scan + compact + RANK-scatter sort -> sortk, meta ----------------
__global__ __launch_bounds__(512) void yolo_selsort_kernel(const u64* __restrict__ keys,
                                                           const u32* __restrict__ hist,
                                                           u64* __restrict__ sortk,
                                                           u32* __restrict__ meta) {
    const int b = blockIdx.x;
    const int tid = threadIdx.x;
    const int lane = tid & 63;
    const int wid = tid >> 6;

    __shared__ u64 skey[KBIG];
    __shared__ u64 sorted[KBIG];
    __shared__ u32 wsum[8];
    __shared__ u32 s_scal[4];
    __shared__ u32 s_cnt;

    const u64* kb = keys + (size_t)b * A_ANCH;
    const u32* hb = hist + (size_t)b * HBINS;

    u32 hg = (tid < HBINS) ? hb[HBINS - 1 - tid] : 0u;
    u32 vals[17];
#pragma unroll
    for (int it = 0; it < 17; ++it) {
        int a = tid + it * 512;
        vals[it] = (a < A_ANCH) ? (u32)(kb[a] >> 32) : 0u;
    }
    {
        u32 pre = hg;
#pragma unroll
        for (int off = 1; off < 64; off <<= 1) {
            u32 o = __shfl_up(pre, off);
            if (lane >= off) pre += o;
        }
        if (lane == 63) wsum[wid] = pre;
        __syncthreads();
        u32 base = 0;
        for (int w = 0; w < wid; ++w) base += wsum[w];
        pre += base;
        u32 run = pre - hg;
        if (tid < HBINS) {
            if (run < 512u && 512u <= pre) { s_scal[0] = (u32)(HBINS - 1 - tid); s_scal[2] = pre; }
            if (tid == HBINS - 1) {
                s_scal[3] = pre;
                if (pre < 512u) { s_scal[0] = 0; s_scal[2] = pre; }
            }
        }
        __syncthreads();
    }
    const u32 Pbin16 = BIN_BASE + s_scal[0];
    const u32 Cfast = s_scal[2];
    const u32 validN = s_scal[3];
    if (tid == 0) { meta[b * 2] = Cfast; meta[b * 2 + 1] = validN; }
    if (Cfast > (u32)KBIG) return;   // degenerate -> fallback path handles

    skey[tid] = 0; skey[tid + 512] = 0;
    if (tid == 0) s_cnt = 0;
    __syncthreads();
#pragma unroll
    for (int it = 0; it < 17; ++it) {
        int a = tid + it * 512;
        u32 v = vals[it];
        bool take = (a < A_ANCH) && (v != 0u) && ((v >> 16) >= Pbin16);
        u64 m = __ballot(take);
        if (m) {
            int fl = __ffsll((unsigned long long)m) - 1;
            u32 basep = 0;
            if (lane == fl) basep = atomicAdd(&s_cnt, (u32)__popcll(m));
            basep = __shfl(basep, fl);
            if (take) {
                u32 pos = basep + (u32)__popcll(m & ((1ull << lane) - 1ull));
                if (pos < (u32)KBIG) skey[pos] = kb[a];
            }
        }
    }
    __syncthreads();

    // ---- rank-scatter sort, descending. Real keys are unique; ties (zero pads)
    // broken by position -> bijective ranks -> identical to bitonic output.
    {
        u64 kA = skey[tid], kB = skey[tid + 512];
        u32 rA = 0, rB = 0;
#pragma unroll 8
        for (int j = 0; j < KBIG; ++j) {
            u64 kj = skey[j];
            rA += (kj > kA) || ((kj == kA) && (j < tid)) ? 1u : 0u;
            rB += (kj > kB) || ((kj == kB) && (j < tid + 512)) ? 1u : 0u;
        }
        sorted[rA] = kA;
        sorted[rB] = kB;
        __syncthreads();
        u64* so = sortk + (size_t)b * KBIG;
        so[tid] = sorted[tid];
        so[tid + 512] = sorted[tid + 512];
    }
}

// ---------------- Kernel 4: mat — 64 rows x 512 cols suppression bits per block ----------------
__global__ __launch_bounds__(512) void yolo_mat_kernel(const u64* __restrict__ sortk,
                                                       const float4* __restrict__ obox,
                                                       u64* __restrict__ rows) {
    const int b = blockIdx.x >> 3;
    const int m = blockIdx.x & 7;
    const int tid = threadIdx.x;
    const int lane = tid & 63;
    const int wid = tid >> 6;
    __shared__ float bx1[512], by1[512], bx2[512], by2[512], bar[512];

    const u64* sk = sortk + (size_t)b * KBIG;
    {
        u64 key = sk[tid];
        int idx = 16383 - (int)((key >> 7) & 16383u);
        if (idx >= A_ANCH || idx < 0) idx = 0;   // pad keys -> inert (invalid, never kept)
        float4 ob = obox[(size_t)b * A_ANCH + idx];
        bx1[tid] = ob.x; by1[tid] = ob.y; bx2[tid] = ob.z; by2[tid] = ob.w;
        bar[tid] = __fmul_rn(__fsub_rn(ob.z, ob.x), __fsub_rn(ob.w, ob.y));
    }
    __syncthreads();

#pragma unroll
    for (int rr = 0; rr < 8; ++rr) {
        int i = m * 64 + wid * 8 + rr;
        float ix1 = bx1[i], iy1 = by1[i], ix2 = bx2[i], iy2 = by2[i], iar = bar[i];
        u64* rowp = rows + ((size_t)b * 512 + i) * 8;
#pragma unroll
        for (int wd = 0; wd < 8; ++wd) {
            int j = wd * 64 + lane;
            float iou = iou_f(ix1, iy1, ix2, iy2, iar, bx1[j], by1[j], bx2[j], by2[j], bar[j]);
            u64 mbit = __ballot((j > i) && (iou > IOU_THR));
            if (lane == 0) rowp[wd] = mbit;
        }
    }
}

union U2 {
    u32 hist[4096];
    struct { u32 eqw[264]; u32 wpre[264]; } tie;
};

// ---------------- Kernel 5: rec (+inlined exact fallback) — greedy recurrence + emit ----------------
__global__ __launch_bounds__(512) void yolo_recfb_kernel(const float* __restrict__ preds,
                                                         const u64* __restrict__ keys,
                                                         const u64* __restrict__ sortk,
                                                         const u64* __restrict__ rowsg,
                                                         const float4* __restrict__ obox,
                                                         const u32* __restrict__ hist,
                                                         const u32* __restrict__ meta,
                                                         float* __restrict__ out) {
    const int b = blockIdx.x;
    const int tid = threadIdx.x;
    const int lane = tid & 63;
    const int wid = tid >> 6;

    union SH {
        struct {                       // rec phase (small)
            u64 skl[512];
            u64 supp[8];
            u64 keep;
            int keptlist[364];
        } r;
        struct {                       // fallback phase (~55 KB)
            U2 u2;
            u64 skey[KBIG];
            float BX1[KBIG], BY1[KBIG], BX2[KBIG], BY2[KBIG], BAR[KBIG];
            int keptlist[364];
            float kx1[364], ky1[364], kx2[364], ky2[364], kar[364];
            u32 kcls[364];
            u64 rows64[64];
        } f;
    };
    __shared__ SH sh;
    __shared__ u32 s_scal[4];
    __shared__ u32 wsum[8];
    __shared__ u32 s_cnt;
    __shared__ u32 s_csupp[2];
    __shared__ u32 s_nkept;

    const u32 Cfast0 = meta[b * 2];
    const u32 validN0 = meta[b * 2 + 1];

    sh.r.skl[tid] = sortk[(size_t)b * KBIG + tid];
    if (tid < 8) sh.r.supp[tid] = 0;
    if (tid == 0) s_nkept = 0;
    __syncthreads();

    bool ok = (Cfast0 <= (u32)KBIG);
    if (ok) {
        const u64* rb = rowsg + (size_t)b * 512 * 8;
        for (int c = 0; c < 8; ++c) {
            if (wid == 0) {
                int i = c * 64 + lane;
                u64 key = sh.r.skl[i];
                float sc = __uint_as_float((u32)(key >> 32));
                u64 ri = rb[(size_t)i * 8 + c];          // diagonal word (in-chunk bits)
                u64 validm = __ballot(sc > CONF_T) & ~sh.r.supp[c];
                u32 rlo = (u32)ri, rhi = (u32)(ri >> 32);
                u64 sup = 0, keep = 0;
#pragma unroll
                for (int i2 = 0; i2 < 64; ++i2) {
                    u64 rr = (((u64)(u32)__builtin_amdgcn_readlane((int)rhi, i2)) << 32) |
                             (u64)(u32)__builtin_amdgcn_readlane((int)rlo, i2);
                    bool ki = (((validm & ~sup) >> i2) & 1ull) != 0;
                    if (ki) { keep |= (1ull << i2); sup |= rr; }
                }
                u32 basek = s_nkept;
                if ((keep >> lane) & 1ull) {
                    u32 slot = basek + (u32)__popcll(keep & ((1ull << lane) - 1ull));
                    sh.r.keptlist[slot] = i;
                }
                if (lane == 0) { sh.r.keep = keep; s_nkept = basek + (u32)__popcll(keep); }
            }
            __syncthreads();
            {
                u64 k = sh.r.keep;
                u64 t = ((k >> lane) & 1ull) ? rb[(size_t)(c * 64 + lane) * 8 + wid] : 0ull;
#pragma unroll
                for (int off = 32; off >= 1; off >>= 1)
                    t |= (u64)__shfl_xor((unsigned long long)t, off, 64);
                if (lane == 0) sh.r.supp[wid] |= t;
            }
            __syncthreads();
            if (s_nkept >= MAX_DET) break;   // forward-only suppression: first 300 fixed
        }
    }
    u32 nk0 = ok ? s_nkept : 0;
    bool fin = ok && ((nk0 >= MAX_DET) || (validN0 <= 512u));

    if (fin) {
        if (tid < MAX_DET) {
            float row[6];
            int t = (tid < (int)(nk0 < MAX_DET ? nk0 : MAX_DET)) ? sh.r.keptlist[tid] : -1;
            if (t >= 0) {
                u64 key = sh.r.skl[t];
                float score = __uint_as_float((u32)(key >> 32));
                int cls = (int)(key & 127u);
                int idx = 16383 - (int)((key >> 7) & 16383u);
                if (idx >= A_ANCH || idx < 0) idx = 0;
                const float* pb = preds + (size_t)b * NROWS * A_ANCH + idx;
                float x = pb[0], y = pb[A_ANCH], w = pb[2 * A_ANCH], h = pb[3 * A_ANCH];
                float hw = __fmul_rn(w, 0.5f), hh = __fmul_rn(h, 0.5f);
                row[0] = __fsub_rn(x, hw);
                row[1] = __fsub_rn(y, hh);
                row[2] = __fadd_rn(x, hw);
                row[3] = __fadd_rn(y, hh);
                row[4] = score;
                row[5] = (float)cls;
            } else {
                row[0] = row[1] = row[2] = row[3] = row[4] = row[5] = (float)NC;
            }
            float* o = out + ((size_t)b * MAX_DET + tid) * 6;
#pragma unroll
            for (int q = 0; q < 6; ++q) o[q] = row[q];
        }
        return;
    }

    // ================= exact fallback (r13-proven body; never taken on bench data) =================
    __syncthreads();
    U2* u2 = &sh.f.u2;
    u64* skey = sh.f.skey;
    float* BX1 = sh.f.BX1; float* BY1 = sh.f.BY1;
    float* BX2 = sh.f.BX2; float* BY2 = sh.f.BY2; float* BAR = sh.f.BAR;
    int* keptlist = sh.f.keptlist;
    float* kx1 = sh.f.kx1; float* ky1 = sh.f.ky1;
    float* kx2 = sh.f.kx2; float* ky2 = sh.f.ky2; float* kar = sh.f.kar;
    u32* kcls = sh.f.kcls;
    u64* rows = sh.f.rows64;

    const u64* kb = keys + (size_t)b * A_ANCH;
    const u32* hb = hist + (size_t)b * HBINS;
    u32 hg = (tid < HBINS) ? hb[HBINS - 1 - tid] : 0u;
    u32 vals[17];
#pragma unroll
    for (int it = 0; it < 17; ++it) {
        int a = tid + it * 512;
        vals[it] = (a < A_ANCH) ? (u32)(kb[a] >> 32) : 0u;
    }
    {
        u32 pre = hg;
#pragma unroll
        for (int off = 1; off < 64; off <<= 1) {
            u32 o = __shfl_up(pre, off);
            if (lane >= off) pre += o;
        }
        if (lane == 63) wsum[wid] = pre;
        __syncthreads();
        u32 base = 0;
        for (int w = 0; w < wid; ++w) base += wsum[w];
        pre += base;
        u32 run = pre - hg;
        if (tid < HBINS) {
            if (run < 512u && 512u <= pre) { s_scal[0] = (u32)(HBINS - 1 - tid); s_scal[2] = pre; }
            if (tid == HBINS - 1) {
                s_scal[3] = pre;
                if (pre < 512u) { s_scal[0] = 0; s_scal[2] = pre; }
            }
        }
        __syncthreads();
    }
    const u32 Pbin16 = BIN_BASE + s_scal[0];
    const u32 Cfast = s_scal[2];
    const u32 validN = s_scal[3];

    for (int pass = 0; pass < 2; ++pass) {
        u32 Ccand;
        if (pass == 0) {
            if (Cfast > (u32)KBIG) continue;
            Ccand = Cfast;
            skey[tid] = 0; skey[tid + 512] = 0;
            if (tid == 0) { s_cnt = 0; s_nkept = 0; s_csupp[0] = 0; s_csupp[1] = 0; }
            __syncthreads();
#pragma unroll
            for (int it = 0; it < 17; ++it) {
                int a = tid + it * 512;
                u32 v = vals[it];
                bool take = (a < A_ANCH) && (v != 0u) && ((v >> 16) >= Pbin16);
                u64 m = __ballot(take);
                if (m) {
                    int fl = __ffsll((unsigned long long)m) - 1;
                    u32 basep = 0;
                    if (lane == fl) basep = atomicAdd(&s_cnt, (u32)__popcll(m));
                    basep = __shfl(basep, fl);
                    if (take) {
                        u32 pos = basep + (u32)__popcll(m & ((1ull << lane) - 1ull));
                        if (pos < (u32)KBIG) skey[pos] = kb[a];
                    }
                }
            }
            __syncthreads();
        } else {
            for (int i = tid; i < 4096; i += 512) u2->hist[i] = 0;
            if (tid == 0) {
                s_scal[0] = 0; s_scal[1] = (u32)KBIG; s_scal[2] = 0;
                s_nkept = 0; s_csupp[0] = 0; s_csupp[1] = 0;
            }
            __syncthreads();
#pragma unroll
            for (int it = 0; it < 17; ++it) {
                int a = tid + it * 512;
                hadd(u2->hist, vals[it] >> 20, a < A_ANCH, lane);
            }
            __syncthreads();
            radix_scan(u2->hist, 4096, 20, s_scal, wsum, tid, lane, wid);
            for (int i = tid; i < 4096; i += 512) u2->hist[i] = 0;
            __syncthreads();
            u32 Pk = s_scal[0];
#pragma unroll
            for (int it = 0; it < 17; ++it) {
                int a = tid + it * 512;
                u32 v = vals[it];
                bool m = (a < A_ANCH) && ((v & 0xFFF00000u) == Pk);
                hadd(u2->hist, (v >> 8) & 4095u, m, lane);
            }
            __syncthreads();
            radix_scan(u2->hist, 4096, 8, s_scal, wsum, tid, lane, wid);
            for (int i = tid; i < 256; i += 512) u2->hist[i] = 0;
            __syncthreads();
            Pk = s_scal[0];
#pragma unroll
            for (int it = 0; it < 17; ++it) {
                int a = tid + it * 512;
                u32 v = vals[it];
                bool m = (a < A_ANCH) && ((v & 0xFFFFFF00u) == Pk);
                hadd(u2->hist, v & 255u, m, lane);
            }
            __syncthreads();
            radix_scan(u2->hist, 256, 0, s_scal, wsum, tid, lane, wid);
            const u32 P = s_scal[0];
            const u32 tEq = s_scal[1];
            if (tid < 264) u2->tie.eqw[tid] = 0;
            __syncthreads();
#pragma unroll
            for (int it = 0; it < 17; ++it) {
                int a = tid + it * 512;
                if (a < A_ANCH && vals[it] == P) atomicOr(&u2->tie.eqw[a >> 5], 1u << (a & 31));
            }
            __syncthreads();
            if (wid == 0) {
                u32 cw[5], loc = 0;
#pragma unroll
                for (int q = 0; q < 5; ++q) {
                    int w2 = lane * 5 + q;
                    u32 e = (w2 < 264) ? u2->tie.eqw[w2] : 0u;
                    cw[q] = (u32)__popc(e); loc += cw[q];
                }
                u32 pre = loc;
#pragma unroll
                for (int off = 1; off < 64; off <<= 1) {
                    u32 o = __shfl_up(pre, off);
                    if (lane >= off) pre += o;
                }
                u32 run = pre - loc;
#pragma unroll
                for (int q = 0; q < 5; ++q) {
                    int w2 = lane * 5 + q;
                    if (w2 < 264) u2->tie.wpre[w2] = run;
                    run += cw[q];
                }
            }
            __syncthreads();
#pragma unroll
            for (int it = 0; it < 17; ++it) {
                int a = tid + it * 512;
                bool take = false;
                if (a < A_ANCH) {
                    u32 v = vals[it];
                    take = v > P;
                    if (!take && v == P) {
                        u32 r = u2->tie.wpre[a >> 5] +
                                (u32)__popc(u2->tie.eqw[a >> 5] & ((1u << (a & 31)) - 1u));
                        take = (r < tEq);
                    }
                }
                u64 m = __ballot(take);
                if (m) {
                    int fl = __ffsll((unsigned long long)m) - 1;
                    u32 basep = 0;
                    if (lane == fl) basep = atomicAdd(&s_scal[2], (u32)__popcll(m));
                    basep = __shfl(basep, fl);
                    if (take) {
                        u32 pos = basep + (u32)__popcll(m & ((1ull << lane) - 1ull));
                        if (pos < (u32)KBIG) skey[pos] = kb[a];
                    }
                }
            }
            __syncthreads();
            Ccand = KBIG;
        }

        {
            u64 vA = skey[tid], vB = skey[tid + 512];
            const u32 iA = (u32)tid, iB = (u32)tid + 512;
#pragma unroll
            for (u32 size = 2; size <= 64; size <<= 1)
#pragma unroll
                for (u32 stride = size >> 1; stride >= 1; stride >>= 1) {
                    vA = bstep(vA, iA, size, stride);
                    vB = bstep(vB, iB, size, stride);
                }
            skey[tid] = vA; skey[tid + 512] = vB;
            __syncthreads();
            for (u32 size = 128; size <= 1024; size <<= 1) {
                for (u32 stride = size >> 1; stride >= 64; stride >>= 1) {
                    u32 i1 = ((tid & ~(int)(stride - 1)) << 1) | (tid & (stride - 1));
                    u32 i2 = i1 + stride;
                    bool desc = ((i1 & size) == 0);
                    u64 x = skey[i1], y = skey[i2];
                    if ((x < y) == desc) { skey[i1] = y; skey[i2] = x; }
                    __syncthreads();
                }
                vA = skey[tid]; vB = skey[tid + 512];
#pragma unroll
                for (u32 stride = 32; stride >= 1; stride >>= 1) {
                    vA = bstep(vA, iA, size, stride);
                    vB = bstep(vB, iB, size, stride);
                }
                skey[tid] = vA; skey[tid + 512] = vB;
                __syncthreads();
            }
        }

#pragma unroll
        for (int q = 0; q < 2; ++q) {
            int t = tid + q * 512;
            u64 key = skey[t];
            int idx = 16383 - (int)((key >> 7) & 16383u);
            if (idx >= A_ANCH || idx < 0) idx = 0;
            float4 ob = obox[(size_t)b * A_ANCH + idx];
            BX1[t] = ob.x; BY1[t] = ob.y; BX2[t] = ob.z; BY2[t] = ob.w;
            BAR[t] = __fmul_rn(__fsub_rn(ob.z, ob.x), __fsub_rn(ob.w, ob.y));
        }
        __syncthreads();

        const int nchunks = (int)((Ccand + 63u) >> 6);
        for (int c = 0; c < nchunks; ++c) {
            int j = c * 64 + lane;
            u64 keyj = skey[j];
            float scj = __uint_as_float((u32)(keyj >> 32));
            u32 clsj = (u32)(keyj & 127u);
            float jx1 = BX1[j], jy1 = BY1[j], jx2 = BX2[j], jy2 = BY2[j], jar = BAR[j];

            u32 nk = s_nkept;
            bool suppbit = false;
            for (u32 k = wid; k < nk; k += 8) {
                bool cm = (kcls[k] == clsj);
                if (__ballot(cm)) {
                    float iou = iou_f(kx1[k], ky1[k], kx2[k], ky2[k], kar[k],
                                      jx1, jy1, jx2, jy2, jar);
                    suppbit |= (cm && (iou > IOU_THR));
                }
            }
            u64 bm = __ballot(suppbit);
            if (bm && lane == 0) {
                atomicOr(&s_csupp[0], (u32)bm);
                atomicOr(&s_csupp[1], (u32)(bm >> 32));
            }
#pragma unroll
            for (int p2 = 0; p2 < 8; ++p2) {
                int i = p2 * 8 + wid;
                int ci = c * 64 + i;
                u32 clsi = (u32)(skey[ci] & 127u);
                u64 m = 0;
                if (__ballot(clsi == clsj)) {
                    float iou = iou_f(BX1[ci], BY1[ci], BX2[ci], BY2[ci], BAR[ci],
                                      jx1, jy1, jx2, jy2, jar);
                    m = __ballot((lane > i) && (iou > IOU_THR));
                }
                if (lane == 0) rows[i] = m;
            }
            __syncthreads();
            if (wid == 0) {
                u64 row = rows[lane];
                u32 rlo = (u32)row, rhi = (u32)(row >> 32);
                u64 csupp = (((u64)s_csupp[1]) << 32) | (u64)s_csupp[0];
                u64 validm = __ballot(scj > CONF_T) & ~csupp;
                u64 supp = 0, keep = 0;
#pragma unroll
                for (int i = 0; i < 64; ++i) {
                    u64 ri = (((u64)(u32)__builtin_amdgcn_readlane((int)rhi, i)) << 32) |
                             (u64)(u32)__builtin_amdgcn_readlane((int)rlo, i);
                    bool ki = (((validm & ~supp) >> i) & 1ull) != 0;
                    if (ki) { keep |= (1ull << i); supp |= ri; }
                }
                u32 basek = s_nkept;
                if ((keep >> lane) & 1ull) {
                    u32 slot = basek + (u32)__popcll(keep & ((1ull << lane) - 1ull));
                    keptlist[slot] = j;
                    kx1[slot] = jx1; ky1[slot] = jy1;
                    kx2[slot] = jx2; ky2[slot] = jy2;
                    kar[slot] = jar; kcls[slot] = clsj;
                }
                if (lane == 0) {
                    s_nkept = basek + (u32)__popcll(keep);
                    s_csupp[0] = 0; s_csupp[1] = 0;
                }
            }
            __syncthreads();
            if (s_nkept >= MAX_DET) break;
        }

        u32 nk = s_nkept;
        bool finished = (nk >= MAX_DET) || (Ccand >= validN) || (pass == 1);
        if (!finished) continue;

        if (tid < MAX_DET) {
            float row[6];
            int t = (tid < (int)(nk < MAX_DET ? nk : MAX_DET)) ? keptlist[tid] : -1;
            if (t >= 0) {
                u64 key = skey[t];
                float score = __uint_as_float((u32)(key >> 32));
                int cls = (int)(key & 127u);
                int idx = 16383 - (int)((key >> 7) & 16383u);
                if (idx >= A_ANCH || idx < 0) idx = 0;
                const float* pb = preds + (size_t)b * NROWS * A_ANCH + idx;
                float x = pb[0], y = pb[A_ANCH], w = pb[2 * A_ANCH], h = pb[3 * A_ANCH];
                float hw = __fmul_rn(w, 0.5f), hh = __fmul_rn(h, 0.5f);
                row[0] = __fsub_rn(x, hw);
                row[1] = __fsub_rn(y, hh);
                row[2] = __fadd_rn(x, hw);
                row[3] = __fadd_rn(y, hh);
                row[4] = score;
                row[5] = (float)cls;
            } else {
                row[0] = row[1] = row[2] = row[3] = row[4] = row[5] = (float)NC;
            }
            float* o = out + ((size_t)b * MAX_DET + tid) * 6;
#pragma unroll
            for (int q = 0; q < 6; ++q) o[q] = row[q];
        }
        break;
    }
}

extern "C" void kernel_launch(void* const* d_in, const int* in_sizes, int n_in,
                              void* d_out, int out_size, void* d_ws, size_t ws_size,
                              hipStream_t stream) {
    const float* preds = (const float*)d_in[0];
    float* out = (float*)d_out;
    int B = in_sizes[0] / (NROWS * A_ANCH);
    float4* obox = (float4*)d_ws;                             // B*8400 f4   (4.30 MB @B=32)
    u64* keys = (u64*)(obox + (size_t)B * A_ANCH);            // B*8400 u64  (2.15 MB)
    u64* sortk = keys + (size_t)B * A_ANCH;                   // B*1024 u64  (262 KB)
    u64* rows = sortk + (size_t)B * KBIG;                     // B*512*8 u64 (1.05 MB)
    u32* hist = (u32*)(rows + (size_t)B * 512 * 8);           // B*256 u32   (32 KB)
    u32* meta = hist + (size_t)B * HBINS;                     // B*2 u32
    yolo_conf_kernel<<<dim3(B * 9), dim3(512), 0, stream>>>(preds, keys, hist);
    yolo_prep_kernel<<<dim3(B * 33), dim3(256), 0, stream>>>(preds, keys, obox, hist);
    yolo_selsort_kernel<<<dim3(B), dim3(512), 0, stream>>>(keys, hist, sortk, meta);
    yolo_mat_kernel<<<dim3(B * 8), dim3(512), 0, stream>>>(sortk, obox, rows);
    yolo_recfb_kernel<<<dim3(B), dim3(512), 0, stream>>>(preds, keys, sortk, rows, obox, hist, meta, out);
}

// Round 15
// 64.441 us; speedup vs baseline: 1.7337x; 1.7337x over previous
//
#include <hip/hip_runtime.h>
#include <stdint.h>

typedef unsigned long long u64;
typedef unsigned int u32;

#define NC 80
#define CONF_T 0.25f
#define IOU_THR 0.45f
#define MAX_DET 300
#define KBIG 1024
#define A_ANCH 8400
#define NROWS 84
#define MAX_WH 7680.0f
#define HBINS 256
#define BIN_BASE 0x3e80u

// adaptive wave histogram add
__device__ __forceinline__ void hadd(u32* h, u32 bin, bool m, int lane) {
    u64 act = __ballot(m);
    if (act == 0) return;
    int fl = __ffsll((unsigned long long)act) - 1;
    u32 fb = __shfl(bin, fl);
    u64 same = __ballot(m && (bin == fb));
    if (lane == fl) atomicAdd(&h[fb], (u32)__popcll(same));
    if (m && (bin != fb)) atomicAdd(&h[bin], 1u);
}

// ---------------- Kernel 1: conf/argmax -> keys; slab 0 zeroes hist ----------------
__global__ __launch_bounds__(512) void yolo_conf_kernel(const float* __restrict__ preds,
                                                        u64* __restrict__ keys,
                                                        u32* __restrict__ hist) {
    int b = blockIdx.x / 9;
    int slab = blockIdx.x % 9;
    if (slab == 0 && threadIdx.x < HBINS) hist[(size_t)b * HBINS + threadIdx.x] = 0;
    int g = slab * 512 + threadIdx.x;
    if (g >= A_ANCH / 2) return;
    int a0 = g * 2;
    const float* base = preds + ((size_t)b * NROWS + 4) * A_ANCH + a0;
    float2 best = *(const float2*)base;
    int bc0 = 0, bc1 = 0;
#pragma unroll 8
    for (int c = 1; c < NC; ++c) {
        float2 v = *(const float2*)(base + (size_t)c * A_ANCH);
        if (v.x > best.x) { best.x = v.x; bc0 = c; }   // strict > = first-max argmax
        if (v.y > best.y) { best.y = v.y; bc1 = c; }
    }
    float s0 = (best.x > CONF_T) ? best.x : 0.0f;
    float s1 = (best.y > CONF_T) ? best.y : 0.0f;
    ulonglong2 kk;
    kk.x = ((u64)__float_as_uint(s0) << 32) | ((u64)(16383 - a0) << 7) | (u64)bc0;
    kk.y = ((u64)__float_as_uint(s1) << 32) | ((u64)(16383 - (a0 + 1)) << 7) | (u64)bc1;
    *(ulonglong2*)(keys + (size_t)b * A_ANCH + a0) = kk;
}

// ---------------- Kernel 2: prep — obox + 256-bin hist ----------------
__global__ __launch_bounds__(256) void yolo_prep_kernel(const float* __restrict__ preds,
                                                        const u64* __restrict__ keys,
                                                        float4* __restrict__ obox,
                                                        u32* __restrict__ hist) {
    __shared__ u32 lh[HBINS];
    const int lane = threadIdx.x & 63;
    int b = blockIdx.x / 33;
    int a = (blockIdx.x % 33) * 256 + threadIdx.x;
    lh[threadIdx.x] = 0;
    __syncthreads();
    u32 bits = 0, bin = 0;
    bool act = a < A_ANCH;
    if (act) {
        u64 key = keys[(size_t)b * A_ANCH + a];
        bits = (u32)(key >> 32);
        int cls = (int)(key & 127u);
        const float* pb = preds + (size_t)b * NROWS * A_ANCH + a;
        float x = pb[0];
        float y = pb[A_ANCH];
        float w = pb[2 * A_ANCH];
        float h = pb[3 * A_ANCH];
        float hw = __fmul_rn(w, 0.5f), hh = __fmul_rn(h, 0.5f);
        float x1 = __fsub_rn(x, hw), x2 = __fadd_rn(x, hw);
        float y1 = __fsub_rn(y, hh), y2 = __fadd_rn(y, hh);
        float off = __fmul_rn((float)cls, MAX_WH);
        float4 oB;
        oB.x = __fadd_rn(x1, off); oB.y = __fadd_rn(y1, off);
        oB.z = __fadd_rn(x2, off); oB.w = __fadd_rn(y2, off);
        obox[(size_t)b * A_ANCH + a] = oB;
        bin = (bits >> 16) - BIN_BASE;
        if (bin > 255u) bin = 255u;
    }
    hadd(lh, bin, act && (bits != 0u), lane);
    __syncthreads();
    u32 c = lh[threadIdx.x];
    if (c) atomicAdd(&hist[(size_t)b * HBINS + threadIdx.x], c);
}

__device__ __forceinline__ float iou_f(float ix1, float iy1, float ix2, float iy2, float iar,
                                       float jx1, float jy1, float jx2, float jy2, float jar) {
    float lx = fmaxf(ix1, jx1), ly = fmaxf(iy1, jy1);
    float rx = fminf(ix2, jx2), ry = fminf(iy2, jy2);
    float ww = fmaxf(__fsub_rn(rx, lx), 0.0f);
    float hh = fmaxf(__fsub_rn(ry, ly), 0.0f);
    float inter = __fmul_rn(ww, hh);
    float den = __fadd_rn(__fsub_rn(__fadd_rn(iar, jar), inter), 1e-7f);
    return __fdiv_rn(inter, den);
}

__device__ __forceinline__ u64 bstep(u64 v, u32 idx, u32 size, u32 stride) {
    u64 v2 = __shfl_xor((unsigned long long)v, (int)stride, 64);
    bool keep_big = (((idx & stride) == 0) == ((idx & size) == 0));
    return ((v > v2) == keep_big) ? v : v2;
}

__device__ __forceinline__ void radix_scan(u32* hist, int nb, int shift, u32* s_scal,
                                           u32* wsum, int tid, int lane, int wid) {
    int per = nb >> 9; if (per == 0) per = 1;
    int na = nb / per;
    u32 rem = s_scal[1];
    u32 Pk = s_scal[0];
    int hi = nb - 1 - per * tid;
    u32 s = 0;
    if (tid < na)
        for (int q = 0; q < per; ++q) s += hist[hi - q];
    u32 pre = s;
#pragma unroll
    for (int off = 1; off < 64; off <<= 1) {
        u32 o = __shfl_up(pre, off);
        if (lane >= off) pre += o;
    }
    if (lane == 63) wsum[wid] = pre;
    __syncthreads();
    u32 base = 0;
    for (int w = 0; w < wid; ++w) base += wsum[w];
    u32 run = base + pre - s;
    if (tid < na) {
        for (int q = 0; q < per; ++q) {
            int d = hi - q;
            u32 g = hist[d];
            if (run < rem && rem <= run + g) {
                s_scal[0] = Pk | ((u32)d << shift);
                s_scal[1] = rem - run;
            }
            run += g;
        }
    }
    __syncthreads();
}

// ---------------- Kernel 3: sel_sort — hist scan + compact + hybrid bitonic sort -> sortk, meta ----------------
__global__ __launch_bounds__(512) void yolo_selsort_kernel(const u64* __restrict__ keys,
                                                           const u32* __restrict__ hist,
                                                           u64* __restrict__ sortk,
                                                           u32* __restrict__ meta) {
    const int b = blockIdx.x;
    const int tid = threadIdx.x;
    const int lane = tid & 63;
    const int wid = tid >> 6;

    __shared__ u64 skey[KBIG];
    __shared__ u32 wsum[8];
    __shared__ u32 s_scal[4];
    __shared__ u32 s_cnt;

    const u64* kb = keys + (size_t)b * A_ANCH;
    const u32* hb = hist + (size_t)b * HBINS;

    u32 hg = (tid < HBINS) ? hb[HBINS - 1 - tid] : 0u;
    u32 vals[17];
#pragma unroll
    for (int it = 0; it < 17; ++it) {
        int a = tid + it * 512;
        vals[it] = (a < A_ANCH) ? (u32)(kb[a] >> 32) : 0u;
    }
    {
        u32 pre = hg;
#pragma unroll
        for (int off = 1; off < 64; off <<= 1) {
            u32 o = __shfl_up(pre, off);
            if (lane >= off) pre += o;
        }
        if (lane == 63) wsum[wid] = pre;
        __syncthreads();
        u32 base = 0;
        for (int w = 0; w < wid; ++w) base += wsum[w];
        pre += base;
        u32 run = pre - hg;
        if (tid < HBINS) {
            if (run < 512u && 512u <= pre) { s_scal[0] = (u32)(HBINS - 1 - tid); s_scal[2] = pre; }
            if (tid == HBINS - 1) {
                s_scal[3] = pre;
                if (pre < 512u) { s_scal[0] = 0; s_scal[2] = pre; }
            }
        }
        __syncthreads();
    }
    const u32 Pbin16 = BIN_BASE + s_scal[0];
    const u32 Cfast = s_scal[2];
    const u32 validN = s_scal[3];
    if (tid == 0) { meta[b * 2] = Cfast; meta[b * 2 + 1] = validN; }
    if (Cfast > (u32)KBIG) return;   // degenerate -> fallback path handles

    skey[tid] = 0; skey[tid + 512] = 0;
    if (tid == 0) s_cnt = 0;
    __syncthreads();
#pragma unroll
    for (int it = 0; it < 17; ++it) {
        int a = tid + it * 512;
        u32 v = vals[it];
        bool take = (a < A_ANCH) && (v != 0u) && ((v >> 16) >= Pbin16);
        u64 m = __ballot(take);
        if (m) {
            int fl = __ffsll((unsigned long long)m) - 1;
            u32 basep = 0;
            if (lane == fl) basep = atomicAdd(&s_cnt, (u32)__popcll(m));
            basep = __shfl(basep, fl);
            if (take) {
                u32 pos = basep + (u32)__popcll(m & ((1ull << lane) - 1ull));
                if (pos < (u32)KBIG) skey[pos] = kb[a];
            }
        }
    }
    __syncthreads();

    // hybrid bitonic sort of 1024, descending, 2 elems/thread (r13-proven)
    {
        u64 vA = skey[tid], vB = skey[tid + 512];
        const u32 iA = (u32)tid, iB = (u32)tid + 512;
#pragma unroll
        for (u32 size = 2; size <= 64; size <<= 1)
#pragma unroll
            for (u32 stride = size >> 1; stride >= 1; stride >>= 1) {
                vA = bstep(vA, iA, size, stride);
                vB = bstep(vB, iB, size, stride);
            }
        skey[tid] = vA; skey[tid + 512] = vB;
        __syncthreads();
        for (u32 size = 128; size <= 1024; size <<= 1) {
            for (u32 stride = size >> 1; stride >= 64; stride >>= 1) {
                u32 i1 = ((tid & ~(int)(stride - 1)) << 1) | (tid & (stride - 1));
                u32 i2 = i1 + stride;
                bool desc = ((i1 & size) == 0);
                u64 x = skey[i1], y = skey[i2];
                if ((x < y) == desc) { skey[i1] = y; skey[i2] = x; }
                __syncthreads();
            }
            vA = skey[tid]; vB = skey[tid + 512];
#pragma unroll
            for (u32 stride = 32; stride >= 1; stride >>= 1) {
                vA = bstep(vA, iA, size, stride);
                vB = bstep(vB, iB, size, stride);
            }
            skey[tid] = vA; skey[tid + 512] = vB;
            __syncthreads();
        }
    }
    u64* so = sortk + (size_t)b * KBIG;
    so[tid] = skey[tid];
    so[tid + 512] = skey[tid + 512];
}

// ---------------- Kernel 4: mat — 64 rows x 512 cols suppression bits per block ----------------
__global__ __launch_bounds__(512) void yolo_mat_kernel(const u64* __restrict__ sortk,
                                                       const float4* __restrict__ obox,
                                                       u64* __restrict__ rows) {
    const int b = blockIdx.x >> 3;
    const int m = blockIdx.x & 7;
    const int tid = threadIdx.x;
    const int lane = tid & 63;
    const int wid = tid >> 6;
    __shared__ float bx1[512], by1[512], bx2[512], by2[512], bar[512];

    const u64* sk = sortk + (size_t)b * KBIG;
    {
        u64 key = sk[tid];
        int idx = 16383 - (int)((key >> 7) & 16383u);
        if (idx >= A_ANCH || idx < 0) idx = 0;   // pad keys -> inert (invalid, never kept)
        float4 ob = obox[(size_t)b * A_ANCH + idx];
        bx1[tid] = ob.x; by1[tid] = ob.y; bx2[tid] = ob.z; by2[tid] = ob.w;
        bar[tid] = __fmul_rn(__fsub_rn(ob.z, ob.x), __fsub_rn(ob.w, ob.y));
    }
    __syncthreads();

#pragma unroll
    for (int rr = 0; rr < 8; ++rr) {
        int i = m * 64 + wid * 8 + rr;
        float ix1 = bx1[i], iy1 = by1[i], ix2 = bx2[i], iy2 = by2[i], iar = bar[i];
        u64* rowp = rows + ((size_t)b * 512 + i) * 8;
#pragma unroll
        for (int wd = 0; wd < 8; ++wd) {
            int j = wd * 64 + lane;
            float iou = iou_f(ix1, iy1, ix2, iy2, iar, bx1[j], by1[j], bx2[j], by2[j], bar[j]);
            u64 mbit = __ballot((j > i) && (iou > IOU_THR));
            if (lane == 0) rowp[wd] = mbit;
        }
    }
}

union U2 {
    u32 hist[4096];
    struct { u32 eqw[264]; u32 wpre[264]; } tie;
};

// ---------------- Kernel 5: rec (+inlined exact fallback) — greedy recurrence + emit ----------------
__global__ __launch_bounds__(512) void yolo_recfb_kernel(const float* __restrict__ preds,
                                                         const u64* __restrict__ keys,
                                                         const u64* __restrict__ sortk,
                                                         const u64* __restrict__ rowsg,
                                                         const float4* __restrict__ obox,
                                                         const u32* __restrict__ hist,
                                                         const u32* __restrict__ meta,
                                                         float* __restrict__ out) {
    const int b = blockIdx.x;
    const int tid = threadIdx.x;
    const int lane = tid & 63;
    const int wid = tid >> 6;

    union SH {
        struct {                       // rec phase (small)
            u64 skl[512];
            u64 supp[8];
            u64 keep;
            int keptlist[364];
        } r;
        struct {                       // fallback phase (~55 KB)
            U2 u2;
            u64 skey[KBIG];
            float BX1[KBIG], BY1[KBIG], BX2[KBIG], BY2[KBIG], BAR[KBIG];
            int keptlist[364];
            float kx1[364], ky1[364], kx2[364], ky2[364], kar[364];
            u32 kcls[364];
            u64 rows64[64];
        } f;
    };
    __shared__ SH sh;
    __shared__ u32 s_scal[4];
    __shared__ u32 wsum[8];
    __shared__ u32 s_cnt;
    __shared__ u32 s_csupp[2];
    __shared__ u32 s_nkept;

    const u32 Cfast0 = meta[b * 2];
    const u32 validN0 = meta[b * 2 + 1];

    sh.r.skl[tid] = sortk[(size_t)b * KBIG + tid];
    if (tid < 8) sh.r.supp[tid] = 0;
    if (tid == 0) s_nkept = 0;
    __syncthreads();

    bool ok = (Cfast0 <= (u32)KBIG);
    if (ok) {
        const u64* rb = rowsg + (size_t)b * 512 * 8;
        for (int c = 0; c < 8; ++c) {
            if (wid == 0) {
                int i = c * 64 + lane;
                u64 key = sh.r.skl[i];
                float sc = __uint_as_float((u32)(key >> 32));
                u64 ri = rb[(size_t)i * 8 + c];          // diagonal word (in-chunk bits)
                u64 validm = __ballot(sc > CONF_T) & ~sh.r.supp[c];
                u32 rlo = (u32)ri, rhi = (u32)(ri >> 32);
                u64 sup = 0, keep = 0;
#pragma unroll
                for (int i2 = 0; i2 < 64; ++i2) {
                    u64 rr = (((u64)(u32)__builtin_amdgcn_readlane((int)rhi, i2)) << 32) |
                             (u64)(u32)__builtin_amdgcn_readlane((int)rlo, i2);
                    bool ki = (((validm & ~sup) >> i2) & 1ull) != 0;
                    if (ki) { keep |= (1ull << i2); sup |= rr; }
                }
                u32 basek = s_nkept;
                if ((keep >> lane) & 1ull) {
                    u32 slot = basek + (u32)__popcll(keep & ((1ull << lane) - 1ull));
                    sh.r.keptlist[slot] = i;
                }
                if (lane == 0) { sh.r.keep = keep; s_nkept = basek + (u32)__popcll(keep); }
            }
            __syncthreads();
            {
                u64 k = sh.r.keep;
                u64 t = ((k >> lane) & 1ull) ? rb[(size_t)(c * 64 + lane) * 8 + wid] : 0ull;
#pragma unroll
                for (int off = 32; off >= 1; off >>= 1)
                    t |= (u64)__shfl_xor((unsigned long long)t, off, 64);
                if (lane == 0) sh.r.supp[wid] |= t;
            }
            __syncthreads();
            if (s_nkept >= MAX_DET) break;   // forward-only suppression: first 300 fixed
        }
    }
    u32 nk0 = ok ? s_nkept : 0;
    bool fin = ok && ((nk0 >= MAX_DET) || (validN0 <= 512u));

    if (fin) {
        if (tid < MAX_DET) {
            float row[6];
            int t = (tid < (int)(nk0 < MAX_DET ? nk0 : MAX_DET)) ? sh.r.keptlist[tid] : -1;
            if (t >= 0) {
                u64 key = sh.r.skl[t];
                float score = __uint_as_float((u32)(key >> 32));
                int cls = (int)(key & 127u);
                int idx = 16383 - (int)((key >> 7) & 16383u);
                if (idx >= A_ANCH || idx < 0) idx = 0;
                const float* pb = preds + (size_t)b * NROWS * A_ANCH + idx;
                float x = pb[0], y = pb[A_ANCH], w = pb[2 * A_ANCH], h = pb[3 * A_ANCH];
                float hw = __fmul_rn(w, 0.5f), hh = __fmul_rn(h, 0.5f);
                row[0] = __fsub_rn(x, hw);
                row[1] = __fsub_rn(y, hh);
                row[2] = __fadd_rn(x, hw);
                row[3] = __fadd_rn(y, hh);
                row[4] = score;
                row[5] = (float)cls;
            } else {
                row[0] = row[1] = row[2] = row[3] = row[4] = row[5] = (float)NC;
            }
            float* o = out + ((size_t)b * MAX_DET + tid) * 6;
#pragma unroll
            for (int q = 0; q < 6; ++q) o[q] = row[q];
        }
        return;
    }

    // ================= exact fallback (r13-proven body; never taken on bench data) =================
    __syncthreads();
    U2* u2 = &sh.f.u2;
    u64* skey = sh.f.skey;
    float* BX1 = sh.f.BX1; float* BY1 = sh.f.BY1;
    float* BX2 = sh.f.BX2; float* BY2 = sh.f.BY2; float* BAR = sh.f.BAR;
    int* keptlist = sh.f.keptlist;
    float* kx1 = sh.f.kx1; float* ky1 = sh.f.ky1;
    float* kx2 = sh.f.kx2; float* ky2 = sh.f.ky2; float* kar = sh.f.kar;
    u32* kcls = sh.f.kcls;
    u64* rows = sh.f.rows64;

    const u64* kb = keys + (size_t)b * A_ANCH;
    const u32* hb = hist + (size_t)b * HBINS;
    u32 hg = (tid < HBINS) ? hb[HBINS - 1 - tid] : 0u;
    u32 vals[17];
#pragma unroll
    for (int it = 0; it < 17; ++it) {
        int a = tid + it * 512;
        vals[it] = (a < A_ANCH) ? (u32)(kb[a] >> 32) : 0u;
    }
    {
        u32 pre = hg;
#pragma unroll
        for (int off = 1; off < 64; off <<= 1) {
            u32 o = __shfl_up(pre, off);
            if (lane >= off) pre += o;
        }
        if (lane == 63) wsum[wid] = pre;
        __syncthreads();
        u32 base = 0;
        for (int w = 0; w < wid; ++w) base += wsum[w];
        pre += base;
        u32 run = pre - hg;
        if (tid < HBINS) {
            if (run < 512u && 512u <= pre) { s_scal[0] = (u32)(HBINS - 1 - tid); s_scal[2] = pre; }
            if (tid == HBINS - 1) {
                s_scal[3] = pre;
                if (pre < 512u) { s_scal[0] = 0; s_scal[2] = pre; }
            }
        }
        __syncthreads();
    }
    const u32 Pbin16 = BIN_BASE + s_scal[0];
    const u32 Cfast = s_scal[2];
    const u32 validN = s_scal[3];

    for (int pass = 0; pass < 2; ++pass) {
        u32 Ccand;
        if (pass == 0) {
            if (Cfast > (u32)KBIG) continue;
            Ccand = Cfast;
            skey[tid] = 0; skey[tid + 512] = 0;
            if (tid == 0) { s_cnt = 0; s_nkept = 0; s_csupp[0] = 0; s_csupp[1] = 0; }
            __syncthreads();
#pragma unroll
            for (int it = 0; it < 17; ++it) {
                int a = tid + it * 512;
                u32 v = vals[it];
                bool take = (a < A_ANCH) && (v != 0u) && ((v >> 16) >= Pbin16);
                u64 m = __ballot(take);
                if (m) {
                    int fl = __ffsll((unsigned long long)m) - 1;
                    u32 basep = 0;
                    if (lane == fl) basep = atomicAdd(&s_cnt, (u32)__popcll(m));
                    basep = __shfl(basep, fl);
                    if (take) {
                        u32 pos = basep + (u32)__popcll(m & ((1ull << lane) - 1ull));
                        if (pos < (u32)KBIG) skey[pos] = kb[a];
                    }
                }
            }
            __syncthreads();
        } else {
            for (int i = tid; i < 4096; i += 512) u2->hist[i] = 0;
            if (tid == 0) {
                s_scal[0] = 0; s_scal[1] = (u32)KBIG; s_scal[2] = 0;
                s_nkept = 0; s_csupp[0] = 0; s_csupp[1] = 0;
            }
            __syncthreads();
#pragma unroll
            for (int it = 0; it < 17; ++it) {
                int a = tid + it * 512;
                hadd(u2->hist, vals[it] >> 20, a < A_ANCH, lane);
            }
            __syncthreads();
            radix_scan(u2->hist, 4096, 20, s_scal, wsum, tid, lane, wid);
            for (int i = tid; i < 4096; i += 512) u2->hist[i] = 0;
            __syncthreads();
            u32 Pk = s_scal[0];
#pragma unroll
            for (int it = 0; it < 17; ++it) {
                int a = tid + it * 512;
                u32 v = vals[it];
                bool m = (a < A_ANCH) && ((v & 0xFFF00000u) == Pk);
                hadd(u2->hist, (v >> 8) & 4095u, m, lane);
            }
            __syncthreads();
            radix_scan(u2->hist, 4096, 8, s_scal, wsum, tid, lane, wid);
            for (int i = tid; i < 256; i += 512) u2->hist[i] = 0;
            __syncthreads();
            Pk = s_scal[0];
#pragma unroll
            for (int it = 0; it < 17; ++it) {
                int a = tid + it * 512;
                u32 v = vals[it];
                bool m = (a < A_ANCH) && ((v & 0xFFFFFF00u) == Pk);
                hadd(u2->hist, v & 255u, m, lane);
            }
            __syncthreads();
            radix_scan(u2->hist, 256, 0, s_scal, wsum, tid, lane, wid);
            const u32 P = s_scal[0];
            const u32 tEq = s_scal[1];
            if (tid < 264) u2->tie.eqw[tid] = 0;
            __syncthreads();
#pragma unroll
            for (int it = 0; it < 17; ++it) {
                int a = tid + it * 512;
                if (a < A_ANCH && vals[it] == P) atomicOr(&u2->tie.eqw[a >> 5], 1u << (a & 31));
            }
            __syncthreads();
            if (wid == 0) {
                u32 cw[5], loc = 0;
#pragma unroll
                for (int q = 0; q < 5; ++q) {
                    int w2 = lane * 5 + q;
                    u32 e = (w2 < 264) ? u2->tie.eqw[w2] : 0u;
                    cw[q] = (u32)__popc(e); loc += cw[q];
                }
                u32 pre = loc;
#pragma unroll
                for (int off = 1; off < 64; off <<= 1) {
                    u32 o = __shfl_up(pre, off);
                    if (lane >= off) pre += o;
                }
                u32 run = pre - loc;
#pragma unroll
                for (int q = 0; q < 5; ++q) {
                    int w2 = lane * 5 + q;
                    if (w2 < 264) u2->tie.wpre[w2] = run;
                    run += cw[q];
                }
            }
            __syncthreads();
#pragma unroll
            for (int it = 0; it < 17; ++it) {
                int a = tid + it * 512;
                bool take = false;
                if (a < A_ANCH) {
                    u32 v = vals[it];
                    take = v > P;
                    if (!take && v == P) {
                        u32 r = u2->tie.wpre[a >> 5] +
                                (u32)__popc(u2->tie.eqw[a >> 5] & ((1u << (a & 31)) - 1u));
                        take = (r < tEq);
                    }
                }
                u64 m = __ballot(take);
                if (m) {
                    int fl = __ffsll((unsigned long long)m) - 1;
                    u32 basep = 0;
                    if (lane == fl) basep = atomicAdd(&s_scal[2], (u32)__popcll(m));
                    basep = __shfl(basep, fl);
                    if (take) {
                        u32 pos = basep + (u32)__popcll(m & ((1ull << lane) - 1ull));
                        if (pos < (u32)KBIG) skey[pos] = kb[a];
                    }
                }
            }
            __syncthreads();
            Ccand = KBIG;
        }

        {
            u64 vA = skey[tid], vB = skey[tid + 512];
            const u32 iA = (u32)tid, iB = (u32)tid + 512;
#pragma unroll
            for (u32 size = 2; size <= 64; size <<= 1)
#pragma unroll
                for (u32 stride = size >> 1; stride >= 1; stride >>= 1) {
                    vA = bstep(vA, iA, size, stride);
                    vB = bstep(vB, iB, size, stride);
                }
            skey[tid] = vA; skey[tid + 512] = vB;
            __syncthreads();
            for (u32 size = 128; size <= 1024; size <<= 1) {
                for (u32 stride = size >> 1; stride >= 64; stride >>= 1) {
                    u32 i1 = ((tid & ~(int)(stride - 1)) << 1) | (tid & (stride - 1));
                    u32 i2 = i1 + stride;
                    bool desc = ((i1 & size) == 0);
                    u64 x = skey[i1], y = skey[i2];
                    if ((x < y) == desc) { skey[i1] = y; skey[i2] = x; }
                    __syncthreads();
                }
                vA = skey[tid]; vB = skey[tid + 512];
#pragma unroll
                for (u32 stride = 32; stride >= 1; stride >>= 1) {
                    vA = bstep(vA, iA, size, stride);
                    vB = bstep(vB, iB, size, stride);
                }
                skey[tid] = vA; skey[tid + 512] = vB;
                __syncthreads();
            }
        }

#pragma unroll
        for (int q = 0; q < 2; ++q) {
            int t = tid + q * 512;
            u64 key = skey[t];
            int idx = 16383 - (int)((key >> 7) & 16383u);
            if (idx >= A_ANCH || idx < 0) idx = 0;
            float4 ob = obox[(size_t)b * A_ANCH + idx];
            BX1[t] = ob.x; BY1[t] = ob.y; BX2[t] = ob.z; BY2[t] = ob.w;
            BAR[t] = __fmul_rn(__fsub_rn(ob.z, ob.x), __fsub_rn(ob.w, ob.y));
        }
        __syncthreads();

        const int nchunks = (int)((Ccand + 63u) >> 6);
        for (int c = 0; c < nchunks; ++c) {
            int j = c * 64 + lane;
            u64 keyj = skey[j];
            float scj = __uint_as_float((u32)(keyj >> 32));
            u32 clsj = (u32)(keyj & 127u);
            float jx1 = BX1[j], jy1 = BY1[j], jx2 = BX2[j], jy2 = BY2[j], jar = BAR[j];

            u32 nk = s_nkept;
            bool suppbit = false;
            for (u32 k = wid; k < nk; k += 8) {
                bool cm = (kcls[k] == clsj);
                if (__ballot(cm)) {
                    float iou = iou_f(kx1[k], ky1[k], kx2[k], ky2[k], kar[k],
                                      jx1, jy1, jx2, jy2, jar);
                    suppbit |= (cm && (iou > IOU_THR));
                }
            }
            u64 bm = __ballot(suppbit);
            if (bm && lane == 0) {
                atomicOr(&s_csupp[0], (u32)bm);
                atomicOr(&s_csupp[1], (u32)(bm >> 32));
            }
#pragma unroll
            for (int p2 = 0; p2 < 8; ++p2) {
                int i = p2 * 8 + wid;
                int ci = c * 64 + i;
                u32 clsi = (u32)(skey[ci] & 127u);
                u64 m = 0;
                if (__ballot(clsi == clsj)) {
                    float iou = iou_f(BX1[ci], BY1[ci], BX2[ci], BY2[ci], BAR[ci],
                                      jx1, jy1, jx2, jy2, jar);
                    m = __ballot((lane > i) && (iou > IOU_THR));
                }
                if (lane == 0) rows[i] = m;
            }
            __syncthreads();
            if (wid == 0) {
                u64 row = rows[lane];
                u32 rlo = (u32)row, rhi = (u32)(row >> 32);
                u64 csupp = (((u64)s_csupp[1]) << 32) | (u64)s_csupp[0];
                u64 validm = __ballot(scj > CONF_T) & ~csupp;
                u64 supp = 0, keep = 0;
#pragma unroll
                for (int i = 0; i < 64; ++i) {
                    u64 ri = (((u64)(u32)__builtin_amdgcn_readlane((int)rhi, i)) << 32) |
                             (u64)(u32)__builtin_amdgcn_readlane((int)rlo, i);
                    bool ki = (((validm & ~supp) >> i) & 1ull) != 0;
                    if (ki) { keep |= (1ull << i); supp |= ri; }
                }
                u32 basek = s_nkept;
                if ((keep >> lane) & 1ull) {
                    u32 slot = basek + (u32)__popcll(keep & ((1ull << lane) - 1ull));
                    keptlist[slot] = j;
                    kx1[slot] = jx1; ky1[slot] = jy1;
                    kx2[slot] = jx2; ky2[slot] = jy2;
                    kar[slot] = jar; kcls[slot] = clsj;
                }
                if (lane == 0) {
                    s_nkept = basek + (u32)__popcll(keep);
                    s_csupp[0] = 0; s_csupp[1] = 0;
                }
            }
            __syncthreads();
            if (s_nkept >= MAX_DET) break;
        }

        u32 nk = s_nkept;
        bool finished = (nk >= MAX_DET) || (Ccand >= validN) || (pass == 1);
        if (!finished) continue;

        if (tid < MAX_DET) {
            float row[6];
            int t = (tid < (int)(nk < MAX_DET ? nk : MAX_DET)) ? keptlist[tid] : -1;
            if (t >= 0) {
                u64 key = skey[t];
                float score = __uint_as_float((u32)(key >> 32));
                int cls = (int)(key & 127u);
                int idx = 16383 - (int)((key >> 7) & 16383u);
                if (idx >= A_ANCH || idx < 0) idx = 0;
                const float* pb = preds + (size_t)b * NROWS * A_ANCH + idx;
                float x = pb[0], y = pb[A_ANCH], w = pb[2 * A_ANCH], h = pb[3 * A_ANCH];
                float hw = __fmul_rn(w, 0.5f), hh = __fmul_rn(h, 0.5f);
                row[0] = __fsub_rn(x, hw);
                row[1] = __fsub_rn(y, hh);
                row[2] = __fadd_rn(x, hw);
                row[3] = __fadd_rn(y, hh);
                row[4] = score;
                row[5] = (float)cls;
            } else {
                row[0] = row[1] = row[2] = row[3] = row[4] = row[5] = (float)NC;
            }
            float* o = out + ((size_t)b * MAX_DET + tid) * 6;
#pragma unroll
            for (int q = 0; q < 6; ++q) o[q] = row[q];
        }
        break;
    }
}

extern "C" void kernel_launch(void* const* d_in, const int* in_sizes, int n_in,
                              void* d_out, int out_size, void* d_ws, size_t ws_size,
                              hipStream_t stream) {
    const float* preds = (const float*)d_in[0];
    float* out = (float*)d_out;
    int B = in_sizes[0] / (NROWS * A_ANCH);
    float4* obox = (float4*)d_ws;                             // B*8400 f4   (4.30 MB @B=32)
    u64* keys = (u64*)(obox + (size_t)B * A_ANCH);            // B*8400 u64  (2.15 MB)
    u64* sortk = keys + (size_t)B * A_ANCH;                   // B*1024 u64  (262 KB)
    u64* rows = sortk + (size_t)B * KBIG;                     // B*512*8 u64 (1.05 MB)
    u32* hist = (u32*)(rows + (size_t)B * 512 * 8);           // B*256 u32   (32 KB)
    u32* meta = hist + (size_t)B * HBINS;                     // B*2 u32
    yolo_conf_kernel<<<dim3(B * 9), dim3(512), 0, stream>>>(preds, keys, hist);
    yolo_prep_kernel<<<dim3(B * 33), dim3(256), 0, stream>>>(preds, keys, obox, hist);
    yolo_selsort_kernel<<<dim3(B), dim3(512), 0, stream>>>(keys, hist, sortk, meta);
    yolo_mat_kernel<<<dim3(B * 8), dim3(512), 0, stream>>>(sortk, obox, rows);
    yolo_recfb_kernel<<<dim3(B), dim3(512), 0, stream>>>(preds, keys, sortk, rows, obox, hist, meta, out);
}